// Round 1
// baseline (130.879 us; speedup 1.0000x reference)
//
#include <hip/hip_runtime.h>
#include <stdint.h>

#define NGRAPH 512
#define NN 64
#define INCH 256
#define TOPK 20
#define EPR 655360

typedef __attribute__((ext_vector_type(8))) short bf16x8;
typedef __attribute__((ext_vector_type(4))) float f32x4;

// ---- LDS map (dword offsets), 13248 dwords = 51.75 KB
// 1024-thr blocks: 2 blocks/CU (wave-limited 32/CU) needs LDS <= 80KB -> OK.
// STG (GEMM partial staging, pairs of waves) aliases XLF/XRF/low-ALF: it is
// dead before XLF/XRF are written (barrier-separated) and long dead before ALF.
#define STG   0      // f32 [8 pair][64 col][20]  (10240 dw used)
#define XLF   0      // f32 [64 d][68]  xl transposed (d-major)
#define XRF   4352   // f32 [64 d][68]
#define ALF   8704   // f32 [64 i][68]  alpha row-major
#define SLOF  13056  // f32 [64]
#define SROF  13120  // f32 [64]
#define ATTO  13184  // f32 [64]
#define SMEM_DW 13248

static __device__ __forceinline__ uint32_t f2bfbits(float f) {
  uint32_t u = __float_as_uint(f);
  return (u + 0x7FFFu + ((u >> 16) & 1u)) >> 16;     // RNE
}
static __device__ __forceinline__ uint32_t pk2(float a, float b) {
  return f2bfbits(a) | (f2bfbits(b) << 16);
}

// ---- pre-kernel: Wl||Wr (f32) -> bf16 pairs in ws (64 KB), once per launch ----
__global__ __launch_bounds__(256) void wpack(const float* __restrict__ Wl,
                                             const float* __restrict__ Wr,
                                             uint32_t* __restrict__ ws) {
  const int t = blockIdx.x * 256 + threadIdx.x;      // 0..16383 (pair index)
  const float* src = (t < 8192) ? Wl : Wr;
  const int p = t & 8191;
  float2 v = *(const float2*)(src + (size_t)p * 2);
  ws[t] = pk2(v.x, v.y);
}

__global__ __launch_bounds__(1024, 8) void gat_fused(
    const float* __restrict__ x,    // [32768,256]
    const uint32_t* __restrict__ ws,// bf16-packed W: [half][64 row][128 pairs]
    const float* __restrict__ blv,  // [64]
    const float* __restrict__ brv,  // [64]
    const float* __restrict__ att,  // [64]
    float* __restrict__ out)        // f32: [idx_i EPR | idx_j EPR | att EPR]
{
  __shared__ __align__(16) uint32_t smemU[SMEM_DW];
  float* smemF = (float*)smemU;

  const int b    = blockIdx.x;
  const int t    = threadIdx.x;
  const int w    = t >> 6;              // wave 0..15
  const int lane = t & 63;
  const int quad = lane >> 4;
  const int lo   = lane & 15;
  const int nodeBase = b * NN;

  if (t < 64) smemF[ATTO + t] = att[t];

  // ---------------- phase 1: MFMA GEMM [64x256]@[256x128], k-split ----------------
  // wave w: half = w>>3 (0->Wl,1->Wr), rows r0..r0+15, k-half kh = w&1 (128 of 256).
  // Each wave: 4 k-steps x 4 col-tiles = 16 MFMA partials; pair (w even, w|1) reduces.
  const int half = w >> 3;
  const int r0   = ((w >> 1) & 3) * 16;
  const int kh   = w & 1;
  const int pair = w >> 1;              // 0..7

  f32x4 acc[4];
  #pragma unroll
  for (int ct = 0; ct < 4; ++ct) acc[ct] = (f32x4){0.f, 0.f, 0.f, 0.f};

  const uint4* wsV = (const uint4*)ws;
  #pragma unroll
  for (int ksl = 0; ksl < 4; ++ksl) {
    const int ks = kh * 4 + ksl;
    const int k0 = ks * 32 + quad * 8;
    const float* ap = x + (size_t)(nodeBase + r0 + lo) * INCH + k0;
    float4 a0 = *(const float4*)ap;
    float4 a1 = *(const float4*)(ap + 4);
    uint4 au = { pk2(a0.x, a0.y), pk2(a0.z, a0.w), pk2(a1.x, a1.y), pk2(a1.z, a1.w) };
    bf16x8 afrag = __builtin_bit_cast(bf16x8, au);
    #pragma unroll
    for (int ct = 0; ct < 4; ++ct) {
      const int n = ct * 16 + lo;                    // W row = output col d
      uint4 bu = wsV[half * 2048 + n * 32 + ks * 4 + quad];
      bf16x8 bfrag = __builtin_bit_cast(bf16x8, bu);
      acc[ct] = __builtin_amdgcn_mfma_f32_16x16x32_bf16(afrag, bfrag, acc[ct], 0, 0, 0);
    }
  }

  // odd-k waves stage partials; even-k waves reduce, add bias, write XLF/XRF transposed
  if (kh) {
    #pragma unroll
    for (int ct = 0; ct < 4; ++ct)
      *(f32x4*)&smemF[STG + pair * 1280 + (ct * 16 + lo) * 20 + quad * 4] = acc[ct];
  }
  __syncthreads();                                   // A: staging visible

  f32x4 vfin[4];
  if (!kh) {
    const float* bias = half ? brv : blv;
    #pragma unroll
    for (int ct = 0; ct < 4; ++ct) {
      f32x4 pv = *(const f32x4*)&smemF[STG + pair * 1280 + (ct * 16 + lo) * 20 + quad * 4];
      const float bb = bias[ct * 16 + lo];
      vfin[ct][0] = acc[ct][0] + pv[0] + bb;
      vfin[ct][1] = acc[ct][1] + pv[1] + bb;
      vfin[ct][2] = acc[ct][2] + pv[2] + bb;
      vfin[ct][3] = acc[ct][3] + pv[3] + bb;
    }
  }
  __syncthreads();                                   // B: staging reads done (STG aliases XLF/XRF)
  if (!kh) {
    const int dstBase = half ? XRF : XLF;
    #pragma unroll
    for (int ct = 0; ct < 4; ++ct)
      *(f32x4*)&smemF[dstBase + (ct * 16 + lo) * 68 + r0 + quad * 4] = vfin[ct];
  }
  __syncthreads();                                   // C: XLF/XRF ready

  // ---------------- Sl/Sr: S*[i] = sum_d att[d]*x*[i][d] (all 1024 threads) -------
  {
    const int idx = t >> 3;                          // 0..127 (64 Sl + 64 Sr)
    const int seg = t & 7;                           // 8 lanes per output
    const int i = idx & 63;
    const int srcB = (idx < 64) ? XLF : XRF;
    float s = 0.f;
    #pragma unroll
    for (int dd = 0; dd < 8; ++dd) {
      const int d = dd * 8 + seg;                    // seg-minor: 2-way banks (free)
      s = fmaf(smemF[ATTO + d], smemF[srcB + d * 68 + i], s);
    }
    s += __shfl_xor(s, 1);
    s += __shfl_xor(s, 2);
    s += __shfl_xor(s, 4);
    if (seg == 0) smemF[((idx < 64) ? SLOF : SROF) + i] = s;
  }
  __syncthreads();                                   // D

  // ---------------- phase 2: alpha = 0.6(Sl+Sr) + 0.4*sum_d a_d|xl+xr| ------------
  {
    const int i0 = t >> 4;                           // 1 row per thread
    const int j0 = (t & 15) * 4;                     // 4 cols per thread
    float pacc[4] = {0.f, 0.f, 0.f, 0.f};
    #pragma unroll 4
    for (int d = 0; d < 64; ++d) {
      const float xl0 = smemF[XLF + d * 68 + i0];
      const f32x4 xr  = *(const f32x4*)&smemF[XRF + d * 68 + j0];
      const float ad  = smemF[ATTO + d];
      #pragma unroll
      for (int c = 0; c < 4; ++c) {
        const float s0 = xl0 + xr[c];
        pacc[c] = fmaf(ad, fabsf(s0), pacc[c]);
      }
    }
    const float sl = smemF[SLOF + i0];
    const f32x4 srv = *(const f32x4*)&smemF[SROF + j0];
    f32x4 v;
    #pragma unroll
    for (int c = 0; c < 4; ++c)
      v[c] = 0.6f * (sl + srv[c]) + 0.4f * pacc[c];
    *(f32x4*)&smemF[ALF + i0 * 68 + j0] = v;
  }
  __syncthreads();                                   // E: alpha ready

  // ---------------- phase 3: wave-parallel bitonic top-20 (4 rows/wave) -----------
  {
    const int rB = w * 4;
    float aq[4], mq[4], Sq[4];
    uint32_t key[4];
    #pragma unroll
    for (int q = 0; q < 4; ++q)
      aq[q] = smemF[ALF + (rB + q) * 68 + lane];     // lane j holds alpha[r][j]

    // m = row max (incl. diagonal, matches ref segment_max)
    #pragma unroll
    for (int q = 0; q < 4; ++q) mq[q] = aq[q];
    #pragma unroll
    for (int msk = 32; msk >= 1; msk >>= 1)
      #pragma unroll
      for (int q = 0; q < 4; ++q)
        mq[q] = fmaxf(mq[q], __shfl_xor(mq[q], msk));

    // S = sum exp(alpha - m) (incl. diagonal)
    #pragma unroll
    for (int q = 0; q < 4; ++q) Sq[q] = __expf(aq[q] - mq[q]);
    #pragma unroll
    for (int msk = 32; msk >= 1; msk >>= 1)
      #pragma unroll
      for (int q = 0; q < 4; ++q)
        Sq[q] += __shfl_xor(Sq[q], msk);

    // order-preserving key, asc-index tie-break, diagonal excluded (same as before)
    #pragma unroll
    for (int q = 0; q < 4; ++q) {
      const uint32_t u = __float_as_uint(aq[q]);
      uint32_t kk = u ^ ((uint32_t)((int32_t)u >> 31) | 0x80000000u);
      kk = (kk & 0xFFFFFFC0u) | (uint32_t)(63 - lane);
      key[q] = (lane == rB + q) ? 0u : kk;
    }

    // bitonic sort 64 keys descending, 21 stages, 4 rows interleaved for ILP
    #pragma unroll
    for (int k = 2; k <= 64; k <<= 1) {
      #pragma unroll
      for (int j = k >> 1; j >= 1; j >>= 1) {
        const bool keep_max = (((lane & k) == 0) == ((lane & j) == 0));
        #pragma unroll
        for (int q = 0; q < 4; ++q) {
          const uint32_t p = __shfl_xor(key[q], j);
          const uint32_t mx = (key[q] > p) ? key[q] : p;
          const uint32_t mn = (key[q] > p) ? p : key[q];
          key[q] = keep_max ? mx : mn;
        }
      }
    }

    // lanes 0..19 hold top-20 (desc); decode + softmax + store
    if (lane < TOPK) {
      #pragma unroll
      for (int q = 0; q < 4; ++q) {
        const int g = nodeBase + rB + q;
        const uint32_t kq = key[q];
        const uint32_t ub = (kq & 0x80000000u) ? (kq ^ 0x80000000u) : ~kq;
        const float alpha = __uint_as_float(ub & 0xFFFFFFC0u);
        const int jj = 63 - (int)(kq & 63u);
        const float va = __expf(alpha - mq[q]) * (1.0f / Sq[q]);
        out[(size_t)g * 20 + lane] = (float)g;
        out[(size_t)EPR + (size_t)g * 20 + lane] = (float)(nodeBase + jj);
        out[2 * (size_t)EPR + (size_t)g * 20 + lane] = va;
      }
    }
  }
}

extern "C" void kernel_launch(void* const* d_in, const int* in_sizes, int n_in,
                              void* d_out, int out_size, void* d_ws, size_t ws_size,
                              hipStream_t stream) {
  const float* x   = (const float*)d_in[0];
  // d_in[1] = edge_index, d_in[2] = batch: fully-connected structure is implicit
  const float* Wl  = (const float*)d_in[3];
  const float* bl  = (const float*)d_in[4];
  const float* Wr  = (const float*)d_in[5];
  const float* br  = (const float*)d_in[6];
  const float* att = (const float*)d_in[7];
  uint32_t* wsW = (uint32_t*)d_ws;                   // 64 KB: bf16-packed Wl||Wr

  wpack<<<dim3(64), dim3(256), 0, stream>>>(Wl, Wr, wsW);
  gat_fused<<<dim3(NGRAPH), dim3(1024), 0, stream>>>(x, wsW, bl, br, att, (float*)d_out);
}

// Round 2
// 130.650 us; speedup vs baseline: 1.0018x; 1.0018x over previous
//
#include <hip/hip_runtime.h>
#include <stdint.h>

#define NGRAPH 512
#define NN 64
#define INCH 256
#define TOPK 20
#define EPR 655360

typedef __attribute__((ext_vector_type(8))) short bf16x8;
typedef __attribute__((ext_vector_type(4))) float f32x4;

// ---- LDS map (dword offsets), 10240 dwords = 40 KB
// STG (GEMM partial staging) aliases XLR/XRR: STG is dead before XLR/XRR are
// written (barrier-separated lifetimes).
#define STG   0      // f32 [8 pair][64 col][20]  (10240 dw)
#define XLR   0      // f32 [64 i][68 d]  xl row-major (stride 68: 2-way banks max)
#define XRR   4352   // f32 [64 j][64 d]  xr row-major, d-group XOR-swizzle by (j&7)
#define SMEM_DW 10240

static __device__ __forceinline__ uint32_t f2bfbits(float f) {
  uint32_t u = __float_as_uint(f);
  return (u + 0x7FFFu + ((u >> 16) & 1u)) >> 16;     // RNE
}
static __device__ __forceinline__ uint32_t pk2(float a, float b) {
  return f2bfbits(a) | (f2bfbits(b) << 16);
}

// order-preserving-key -> alpha (low 6 bits were the index tie-break)
static __device__ __forceinline__ float keyalpha(uint32_t k) {
  uint32_t ub = (k & 0x80000000u) ? (k ^ 0x80000000u) : ~k;
  return __uint_as_float(ub & 0xFFFFFFC0u);
}

// butterfly sum over 64 lanes; stages 1,2 on the VALU (DPP quad_perm), rest ds_swizzle
static __device__ __forceinline__ float redsum64(float v) {
  int p;
  p = __builtin_amdgcn_update_dpp(0, __float_as_int(v), 0xB1, 0xF, 0xF, true); // xor 1
  v += __int_as_float(p);
  p = __builtin_amdgcn_update_dpp(0, __float_as_int(v), 0x4E, 0xF, 0xF, true); // xor 2
  v += __int_as_float(p);
  v += __shfl_xor(v, 4);
  v += __shfl_xor(v, 8);
  v += __shfl_xor(v, 16);
  v += __shfl_xor(v, 32);
  return v;
}

// ---- pre-kernel: Wl||Wr (f32) -> bf16 pairs in ws (64 KB), once per launch ----
__global__ __launch_bounds__(256) void wpack(const float* __restrict__ Wl,
                                             const float* __restrict__ Wr,
                                             uint32_t* __restrict__ ws) {
  const int t = blockIdx.x * 256 + threadIdx.x;      // 0..16383 (pair index)
  const float* src = (t < 8192) ? Wl : Wr;
  const int p = t & 8191;
  float2 v = *(const float2*)(src + (size_t)p * 2);
  ws[t] = pk2(v.x, v.y);
}

__global__ __launch_bounds__(1024, 8) void gat_fused(
    const float* __restrict__ x,    // [32768,256]
    const uint32_t* __restrict__ ws,// bf16-packed W: [half][64 row][128 pairs]
    const float* __restrict__ blv,  // [64]
    const float* __restrict__ brv,  // [64]
    const float* __restrict__ att,  // [64]
    float* __restrict__ out)        // f32: [idx_i EPR | idx_j EPR | att EPR]
{
  __shared__ __align__(16) uint32_t smemU[SMEM_DW];
  float* smemF = (float*)smemU;

  const int b    = blockIdx.x;
  const int t    = threadIdx.x;
  const int w    = t >> 6;              // wave 0..15
  const int lane = t & 63;
  const int quad = lane >> 4;
  const int lo   = lane & 15;
  const int nodeBase = b * NN;

  // ---------------- phase 1: MFMA GEMM [64x256]@[256x128], k-split ----------------
  // wave w: half = w>>3 (0->Wl,1->Wr), rows r0..r0+15, k-half kh = w&1 (128 of 256).
  const int half = w >> 3;
  const int r0   = ((w >> 1) & 3) * 16;
  const int kh   = w & 1;
  const int pair = w >> 1;              // 0..7

  f32x4 acc[4];
  #pragma unroll
  for (int ct = 0; ct < 4; ++ct) acc[ct] = (f32x4){0.f, 0.f, 0.f, 0.f};

  const uint4* wsV = (const uint4*)ws;
  #pragma unroll
  for (int ksl = 0; ksl < 4; ++ksl) {
    const int ks = kh * 4 + ksl;
    const int k0 = ks * 32 + quad * 8;
    const float* ap = x + (size_t)(nodeBase + r0 + lo) * INCH + k0;
    float4 a0 = *(const float4*)ap;
    float4 a1 = *(const float4*)(ap + 4);
    uint4 au = { pk2(a0.x, a0.y), pk2(a0.z, a0.w), pk2(a1.x, a1.y), pk2(a1.z, a1.w) };
    bf16x8 afrag = __builtin_bit_cast(bf16x8, au);
    #pragma unroll
    for (int ct = 0; ct < 4; ++ct) {
      const int n = ct * 16 + lo;                    // W row = output col d
      uint4 bu = wsV[half * 2048 + n * 32 + ks * 4 + quad];
      bf16x8 bfrag = __builtin_bit_cast(bf16x8, bu);
      acc[ct] = __builtin_amdgcn_mfma_f32_16x16x32_bf16(afrag, bfrag, acc[ct], 0, 0, 0);
    }
  }

  // odd-k waves stage partials; even-k waves reduce + bias, then write row-major
  if (kh) {
    #pragma unroll
    for (int ct = 0; ct < 4; ++ct)
      *(f32x4*)&smemF[STG + pair * 1280 + (ct * 16 + lo) * 20 + quad * 4] = acc[ct];
  }
  __syncthreads();                                   // A: staging visible

  f32x4 vfin[4];
  if (!kh) {
    const float* bias = half ? brv : blv;
    #pragma unroll
    for (int ct = 0; ct < 4; ++ct) {
      f32x4 pv = *(const f32x4*)&smemF[STG + pair * 1280 + (ct * 16 + lo) * 20 + quad * 4];
      const float bb = bias[ct * 16 + lo];
      vfin[ct][0] = acc[ct][0] + pv[0] + bb;
      vfin[ct][1] = acc[ct][1] + pv[1] + bb;
      vfin[ct][2] = acc[ct][2] + pv[2] + bb;
      vfin[ct][3] = acc[ct][3] + pv[3] + bb;
    }
  }
  __syncthreads();                                   // B: staging reads done (STG aliases XLR/XRR)
  if (!kh) {
    if (half == 0) {
      #pragma unroll
      for (int ct = 0; ct < 4; ++ct)
        #pragma unroll
        for (int rg = 0; rg < 4; ++rg)
          smemF[XLR + (r0 + quad * 4 + rg) * 68 + ct * 16 + lo] = vfin[ct][rg];
    } else {
      #pragma unroll
      for (int ct = 0; ct < 4; ++ct)
        #pragma unroll
        for (int rg = 0; rg < 4; ++rg) {
          const int row = r0 + quad * 4 + rg;
          const int dsw = (ct * 16 + lo) ^ ((row & 7) << 2);
          smemF[XRR + row * 64 + dsw] = vfin[ct][rg];
        }
    }
  }
  __syncthreads();                                   // C: XLR/XRR ready — last barrier

  // ============== phases 2+3, fully per-wave: wave w owns rows rB..rB+3 ==========
  const int rB = w * 4;

  // xl row values: lane d holds xl[rB+q][d]  (readlane source)
  float xlv[4];
  #pragma unroll
  for (int q = 0; q < 4; ++q)
    xlv[q] = smemF[XLR + (rB + q) * 68 + lane];

  // Sl[rB+q] = sum_d att[d]*xl[rB+q][d]  (butterfly; uniform result)
  const float attv = att[lane];
  float sl[4];
  #pragma unroll
  for (int q = 0; q < 4; ++q)
    sl[q] = redsum64(attv * xlv[q]);

  // main loop: lane j accumulates over d; xr[j][*] register-chunked, xl via readlane,
  // att via SGPR (uniform load). Sr folded in-register.
  float pacc[4] = {0.f, 0.f, 0.f, 0.f};
  float srp = 0.f;
  const int xrb = XRR + lane * 64;
  const int sw  = lane & 7;
  #pragma unroll
  for (int c = 0; c < 4; ++c) {
    f32x4 xrc[4];
    #pragma unroll
    for (int g = 0; g < 4; ++g)
      xrc[g] = *(const f32x4*)&smemF[xrb + (((c * 4 + g) ^ sw) << 2)];
    #pragma unroll
    for (int dl = 0; dl < 16; ++dl) {
      const int d = c * 16 + dl;
      const float xv = xrc[dl >> 2][dl & 3];
      const float av = att[d];                       // uniform -> s_load/SGPR
      srp = fmaf(av, xv, srp);
      #pragma unroll
      for (int q = 0; q < 4; ++q) {
        const float xls = __int_as_float(
            __builtin_amdgcn_readlane(__float_as_int(xlv[q]), d));
        pacc[q] = fmaf(av, fabsf(xls + xv), pacc[q]);
      }
    }
  }

  // alpha[rB+q][lane], kept in registers (already the sort layout)
  float aq[4];
  #pragma unroll
  for (int q = 0; q < 4; ++q)
    aq[q] = 0.6f * (sl[q] + srp) + 0.4f * pacc[q];

  // order-preserving keys, asc-index tie-break, diagonal excluded
  uint32_t key[4];
  #pragma unroll
  for (int q = 0; q < 4; ++q) {
    const uint32_t u = __float_as_uint(aq[q]);
    uint32_t kk = u ^ ((uint32_t)((int32_t)u >> 31) | 0x80000000u);
    kk = (kk & 0xFFFFFFC0u) | (uint32_t)(63 - lane);
    key[q] = (lane == rB + q) ? 0u : kk;
  }

  // bitonic sort 64 desc; j=1,2 stages on VALU via DPP quad_perm
  #pragma unroll
  for (int k = 2; k <= 64; k <<= 1) {
    #pragma unroll
    for (int j = k >> 1; j >= 1; j >>= 1) {
      const bool keep_max = (((lane & k) == 0) == ((lane & j) == 0));
      #pragma unroll
      for (int q = 0; q < 4; ++q) {
        uint32_t p;
        if (j == 1)
          p = (uint32_t)__builtin_amdgcn_update_dpp(0, (int)key[q], 0xB1, 0xF, 0xF, true);
        else if (j == 2)
          p = (uint32_t)__builtin_amdgcn_update_dpp(0, (int)key[q], 0x4E, 0xF, 0xF, true);
        else
          p = (uint32_t)__shfl_xor((int)key[q], j);
        const uint32_t mx = (key[q] > p) ? key[q] : p;
        const uint32_t mn = (key[q] > p) ? p : key[q];
        key[q] = keep_max ? mx : mn;
      }
    }
  }

  // m from sorted[0] + diagonal (m cancels in the softmax ratio, truncation harmless);
  // S = sum_j exp(alpha - m) over all 64 (incl. self loop), butterfly-reduced.
  float mq[4], Sq[4];
  #pragma unroll
  for (int q = 0; q < 4; ++q) {
    const uint32_t tk = (uint32_t)__builtin_amdgcn_readlane((int)key[q], 0);
    const float topa  = keyalpha(tk);
    const float adiag = __int_as_float(
        __builtin_amdgcn_readlane(__float_as_int(aq[q]), rB + q));
    mq[q] = fmaxf(topa, adiag);
    Sq[q] = redsum64(__expf(aq[q] - mq[q]));
  }

  // lanes 0..19 hold top-20 desc; decode + softmax + store
  if (lane < TOPK) {
    #pragma unroll
    for (int q = 0; q < 4; ++q) {
      const int g = nodeBase + rB + q;
      const uint32_t kq = key[q];
      const float alpha = keyalpha(kq);
      const int jj = 63 - (int)(kq & 63u);
      const float va = __expf(alpha - mq[q]) * (1.0f / Sq[q]);
      out[(size_t)g * 20 + lane] = (float)g;
      out[(size_t)EPR + (size_t)g * 20 + lane] = (float)(nodeBase + jj);
      out[2 * (size_t)EPR + (size_t)g * 20 + lane] = va;
    }
  }
}

extern "C" void kernel_launch(void* const* d_in, const int* in_sizes, int n_in,
                              void* d_out, int out_size, void* d_ws, size_t ws_size,
                              hipStream_t stream) {
  const float* x   = (const float*)d_in[0];
  // d_in[1] = edge_index, d_in[2] = batch: fully-connected structure is implicit
  const float* Wl  = (const float*)d_in[3];
  const float* bl  = (const float*)d_in[4];
  const float* Wr  = (const float*)d_in[5];
  const float* br  = (const float*)d_in[6];
  const float* att = (const float*)d_in[7];
  uint32_t* wsW = (uint32_t*)d_ws;                   // 64 KB: bf16-packed Wl||Wr

  wpack<<<dim3(64), dim3(256), 0, stream>>>(Wl, Wr, wsW);
  gat_fused<<<dim3(NGRAPH), dim3(1024), 0, stream>>>(x, wsW, bl, br, att, (float*)d_out);
}

// Round 3
// 124.558 us; speedup vs baseline: 1.0507x; 1.0489x over previous
//
#include <hip/hip_runtime.h>
#include <stdint.h>

#define NGRAPH 512
#define NN 64
#define INCH 256
#define TOPK 20
#define EPR 655360
// ws layout: [0, 64KB) = W bf16 fragment-ordered; [64KB, 64KB+16MB) = x bf16 fragment-ordered
#define WS_NEED ((size_t)65536 + (size_t)16777216)

typedef __attribute__((ext_vector_type(8))) short bf16x8;
typedef __attribute__((ext_vector_type(4))) float f32x4;

// ---- LDS map (dword offsets), 8704 dwords = 34 KB
#define XLR 0     // f32 [64 i][68]  xl row-major (stride 68: banks spread 4/row)
#define XRR 4352  // f32 [64 j][68]  xr row-major
#define SMEM_DW 8704

static __device__ __forceinline__ uint32_t f2bfbits(float f) {
  uint32_t u = __float_as_uint(f);
  return (u + 0x7FFFu + ((u >> 16) & 1u)) >> 16;     // RNE
}
static __device__ __forceinline__ uint32_t pk2(float a, float b) {
  return f2bfbits(a) | (f2bfbits(b) << 16);
}
static __device__ __forceinline__ float keyalpha(uint32_t k) {
  uint32_t ub = (k & 0x80000000u) ? (k ^ 0x80000000u) : ~k;
  return __uint_as_float(ub & 0xFFFFFFC0u);
}
// butterfly sum over 64 lanes; stages 1,2 on VALU (DPP quad_perm), rest ds_swizzle
static __device__ __forceinline__ float redsum64(float v) {
  int p;
  p = __builtin_amdgcn_update_dpp(0, __float_as_int(v), 0xB1, 0xF, 0xF, true); // xor 1
  v += __int_as_float(p);
  p = __builtin_amdgcn_update_dpp(0, __float_as_int(v), 0x4E, 0xF, 0xF, true); // xor 2
  v += __int_as_float(p);
  v += __shfl_xor(v, 4);
  v += __shfl_xor(v, 8);
  v += __shfl_xor(v, 16);
  v += __shfl_xor(v, 32);
  return v;
}

// ---- W -> bf16, MFMA-fragment order: uint4 idx = half*2048 + ks*256 + ct*64 + quad*16 + lo
__global__ __launch_bounds__(256) void wpack2(const float* __restrict__ Wl,
                                              const float* __restrict__ Wr,
                                              uint4* __restrict__ wsW) {
  const int t = blockIdx.x * 256 + threadIdx.x;      // 0..4095
  const int lo = t & 15, quad = (t >> 4) & 3, ct = (t >> 6) & 3;
  const int ks = (t >> 8) & 7, half = (t >> 11) & 1;
  const int n = ct * 16 + lo, k0 = ks * 32 + quad * 8;
  const float* src = half ? Wr : Wl;
  const float4* s4 = (const float4*)(src + (size_t)n * INCH + k0);
  float4 a0 = s4[0], a1 = s4[1];
  wsW[t] = (uint4){ pk2(a0.x, a0.y), pk2(a0.z, a0.w), pk2(a1.x, a1.y), pk2(a1.z, a1.w) };
}

// ---- x -> bf16, fragment order: uint4 idx = b*2048 + ks*256 + rt*64 + quad*16 + lo
__global__ __launch_bounds__(256) void xpack(const float* __restrict__ x,
                                             uint4* __restrict__ xp) {
  const int t = blockIdx.x * 256 + threadIdx.x;      // 0..1048575
  const int lo = t & 15, quad = (t >> 4) & 3, rt = (t >> 6) & 3;
  const int ks = (t >> 8) & 7, b = t >> 11;
  const int row = b * 64 + rt * 16 + lo, k0 = ks * 32 + quad * 8;
  const float4* s4 = (const float4*)(x + (size_t)row * INCH + k0);
  float4 a0 = s4[0], a1 = s4[1];
  xp[t] = (uint4){ pk2(a0.x, a0.y), pk2(a0.z, a0.w), pk2(a1.x, a1.y), pk2(a1.z, a1.w) };
}

template <bool XP>
__global__ __launch_bounds__(512, 4) void gat_fused(
    const float* __restrict__ x,    // [32768,256] (used when !XP)
    const uint4* __restrict__ wsV,  // W frag-ordered; +4096 = x frag-ordered (XP)
    const float* __restrict__ blv,
    const float* __restrict__ brv,
    const float* __restrict__ att,
    float* __restrict__ out)        // f32: [idx_i EPR | idx_j EPR | att EPR]
{
  __shared__ __align__(16) uint32_t smemU[SMEM_DW];
  float* smemF = (float*)smemU;

  const int b    = blockIdx.x;
  const int t    = threadIdx.x;
  const int w    = t >> 6;              // wave 0..7
  const int lane = t & 63;
  const int quad = lane >> 4;
  const int lo   = lane & 15;
  const int nodeBase = b * NN;

  const float attv = att[lane];         // early, hides latency

  // ---------------- phase 1: MFMA GEMM [64x256]@[256x128], full-K per wave --------
  // wave w: half = w>>2 (0->Wl,1->Wr), row tile rt = w&3 (rows rt*16..+15)
  const int half = w >> 2;
  const int rt   = w & 3;
  const int r0   = rt * 16;
  const uint4* xpV = wsV + 4096;

  f32x4 acc[4];
  #pragma unroll
  for (int ct = 0; ct < 4; ++ct) acc[ct] = (f32x4){0.f, 0.f, 0.f, 0.f};

  #pragma unroll
  for (int ks = 0; ks < 8; ++ks) {
    bf16x8 afrag;
    if constexpr (XP) {
      uint4 au = xpV[(size_t)b * 2048 + ks * 256 + rt * 64 + quad * 16 + lo]; // dense 1KB/instr
      afrag = __builtin_bit_cast(bf16x8, au);
    } else {
      const int k0 = ks * 32 + quad * 8;
      const float* ap = x + (size_t)(nodeBase + r0 + lo) * INCH + k0;
      float4 a0 = *(const float4*)ap;
      float4 a1 = *(const float4*)(ap + 4);
      uint4 au = { pk2(a0.x, a0.y), pk2(a0.z, a0.w), pk2(a1.x, a1.y), pk2(a1.z, a1.w) };
      afrag = __builtin_bit_cast(bf16x8, au);
    }
    #pragma unroll
    for (int ct = 0; ct < 4; ++ct) {
      uint4 bu = wsV[half * 2048 + ks * 256 + ct * 64 + quad * 16 + lo];      // dense 1KB/instr
      bf16x8 bfrag = __builtin_bit_cast(bf16x8, bu);
      acc[ct] = __builtin_amdgcn_mfma_f32_16x16x32_bf16(afrag, bfrag, acc[ct], 0, 0, 0);
    }
  }

  // epilogue: C/D (col=lo -> d, row=quad*4+rg -> node) + bias -> row-major LDS
  {
    const float* bias = half ? brv : blv;
    const int dstBase = half ? XRR : XLR;
    #pragma unroll
    for (int ct = 0; ct < 4; ++ct) {
      const int d = ct * 16 + lo;
      const float bb = bias[d];
      #pragma unroll
      for (int rg = 0; rg < 4; ++rg)
        smemF[dstBase + (r0 + quad * 4 + rg) * 68 + d] = acc[ct][rg] + bb;
    }
  }
  __syncthreads();                                   // the only barrier

  // ============== phases 2+3, per-wave: wave w owns rows rB..rB+7 ================
  const int rB = w * 8;

  float xlv[8];
  #pragma unroll
  for (int q = 0; q < 8; ++q)
    xlv[q] = smemF[XLR + (rB + q) * 68 + lane];      // lane d holds xl[rB+q][d]

  float sl[8];
  #pragma unroll
  for (int q = 0; q < 8; ++q)
    sl[q] = redsum64(attv * xlv[q]);                 // uniform Sl per row

  // lane j: iterate d; xr[j][*] register-chunked; xl & att broadcast via readlane
  float pacc[8];
  #pragma unroll
  for (int q = 0; q < 8; ++q) pacc[q] = 0.f;
  float srp = 0.f;
  const int xrb = XRR + lane * 68;
  #pragma unroll
  for (int c = 0; c < 4; ++c) {
    f32x4 xrc[4];
    #pragma unroll
    for (int g = 0; g < 4; ++g)
      xrc[g] = *(const f32x4*)&smemF[xrb + c * 16 + g * 4];
    #pragma unroll
    for (int dl = 0; dl < 16; ++dl) {
      const int d = c * 16 + dl;
      const float xv = xrc[dl >> 2][dl & 3];
      const float av = __int_as_float(
          __builtin_amdgcn_readlane(__float_as_int(attv), d));
      srp = fmaf(av, xv, srp);
      #pragma unroll
      for (int q = 0; q < 8; ++q) {
        const float xls = __int_as_float(
            __builtin_amdgcn_readlane(__float_as_int(xlv[q]), d));
        pacc[q] = fmaf(av, fabsf(xls + xv), pacc[q]);
      }
    }
  }

  float aq[8];
  #pragma unroll
  for (int q = 0; q < 8; ++q)
    aq[q] = 0.6f * (sl[q] + srp) + 0.4f * pacc[q];

  // order-preserving keys, asc-index tie-break, diagonal excluded
  uint32_t key[8];
  #pragma unroll
  for (int q = 0; q < 8; ++q) {
    const uint32_t u = __float_as_uint(aq[q]);
    uint32_t kk = u ^ ((uint32_t)((int32_t)u >> 31) | 0x80000000u);
    kk = (kk & 0xFFFFFFC0u) | (uint32_t)(63 - lane);
    key[q] = (lane == rB + q) ? 0u : kk;
  }

  // bitonic sort 64 desc; j=1,2 stages on VALU via DPP quad_perm; 8 rows interleaved
  #pragma unroll
  for (int k = 2; k <= 64; k <<= 1) {
    #pragma unroll
    for (int j = k >> 1; j >= 1; j >>= 1) {
      const bool keep_max = (((lane & k) == 0) == ((lane & j) == 0));
      #pragma unroll
      for (int q = 0; q < 8; ++q) {
        uint32_t p;
        if (j == 1)
          p = (uint32_t)__builtin_amdgcn_update_dpp(0, (int)key[q], 0xB1, 0xF, 0xF, true);
        else if (j == 2)
          p = (uint32_t)__builtin_amdgcn_update_dpp(0, (int)key[q], 0x4E, 0xF, 0xF, true);
        else
          p = (uint32_t)__shfl_xor((int)key[q], j);
        const uint32_t mx = (key[q] > p) ? key[q] : p;
        const uint32_t mn = (key[q] > p) ? p : key[q];
        key[q] = keep_max ? mx : mn;
      }
    }
  }

  // m from sorted[0] + diagonal; S = full-row sum exp(alpha - m) (incl. self loop)
  float mq[8], Sq[8];
  #pragma unroll
  for (int q = 0; q < 8; ++q) {
    const uint32_t tk = (uint32_t)__builtin_amdgcn_readlane((int)key[q], 0);
    const float topa  = keyalpha(tk);
    const float adiag = __int_as_float(
        __builtin_amdgcn_readlane(__float_as_int(aq[q]), rB + q));
    mq[q] = fmaxf(topa, adiag);
    Sq[q] = redsum64(__expf(aq[q] - mq[q]));
  }

  // lanes 0..19 hold top-20 desc; decode + softmax + store (80B runs, coalesced)
  if (lane < TOPK) {
    #pragma unroll
    for (int q = 0; q < 8; ++q) {
      const int g = nodeBase + rB + q;
      const uint32_t kq = key[q];
      const float alpha = keyalpha(kq);
      const int jj = 63 - (int)(kq & 63u);
      const float va = __expf(alpha - mq[q]) * (1.0f / Sq[q]);
      out[(size_t)g * 20 + lane] = (float)g;
      out[(size_t)EPR + (size_t)g * 20 + lane] = (float)(nodeBase + jj);
      out[2 * (size_t)EPR + (size_t)g * 20 + lane] = va;
    }
  }
}

extern "C" void kernel_launch(void* const* d_in, const int* in_sizes, int n_in,
                              void* d_out, int out_size, void* d_ws, size_t ws_size,
                              hipStream_t stream) {
  const float* x   = (const float*)d_in[0];
  // d_in[1] = edge_index, d_in[2] = batch: fully-connected structure is implicit
  const float* Wl  = (const float*)d_in[3];
  const float* bl  = (const float*)d_in[4];
  const float* Wr  = (const float*)d_in[5];
  const float* br  = (const float*)d_in[6];
  const float* att = (const float*)d_in[7];
  uint4* wsW = (uint4*)d_ws;                         // [0,4096) uint4 = W

  wpack2<<<dim3(16), dim3(256), 0, stream>>>(Wl, Wr, wsW);
  if (ws_size >= WS_NEED) {
    xpack<<<dim3(4096), dim3(256), 0, stream>>>(x, wsW + 4096);
    gat_fused<true><<<dim3(NGRAPH), dim3(512), 0, stream>>>(
        x, wsW, bl, br, att, (float*)d_out);
  } else {
    gat_fused<false><<<dim3(NGRAPH), dim3(512), 0, stream>>>(
        x, wsW, bl, br, att, (float*)d_out);
  }
}